// Round 4
// baseline (251.696 us; speedup 1.0000x reference)
//
#include <hip/hip_runtime.h>
#include <math.h>

#define N_NODES 10000
#define N_EDGES 160000
#define N_FEAT  512
#define HEADS   8
#define HID     128

typedef __attribute__((ext_vector_type(8))) short bf16x8;
typedef __attribute__((ext_vector_type(4))) float f32x4;
typedef __attribute__((ext_vector_type(2))) float v2f;

// ---------------------------------------------------------------------------
// fp32 <-> bf16 helpers
// ---------------------------------------------------------------------------
__device__ inline unsigned short f2bf_rne(float f) {
  unsigned int u = __float_as_uint(f);
  unsigned int r = u + 0x7fffu + ((u >> 16) & 1u);
  return (unsigned short)(r >> 16);
}
__device__ inline float bf2f(unsigned int b) {
  return __uint_as_float(b << 16);
}

// ---------------------------------------------------------------------------
// split body: fp32 [R][K] -> bf16 in MFMA-fragment-major layout.
// lo == nullptr skips the lo plane (all GEMM operands are bf16-only now;
// scores were moved to an exact fp32 GEMV via the w-tilde trick).
// ---------------------------------------------------------------------------
__device__ inline void split_body(const float* __restrict__ in,
                                  unsigned short* __restrict__ hi,
                                  unsigned short* __restrict__ lo,
                                  int R, int K8, int idx) {
  int r = idx & 15;
  int t = idx >> 4;
  int kq = t % K8;
  int rb = t / K8;
  int row = rb * 16 + r;
  float v[8] = {0.f, 0.f, 0.f, 0.f, 0.f, 0.f, 0.f, 0.f};
  if (row < R) {
    const float* p = in + (size_t)row * (K8 * 8) + kq * 8;
    float4 a = *(const float4*)p;
    float4 b = *(const float4*)(p + 4);
    v[0] = a.x; v[1] = a.y; v[2] = a.z; v[3] = a.w;
    v[4] = b.x; v[5] = b.y; v[6] = b.z; v[7] = b.w;
  }
  union { unsigned short u[8]; int4 v4; } H, L;
  #pragma unroll
  for (int e = 0; e < 8; ++e) {
    unsigned short hb_ = f2bf_rne(v[e]);
    H.u[e] = hb_;
    L.u[e] = f2bf_rne(v[e] - bf2f(hb_));
  }
  *(int4*)&hi[(size_t)idx * 8] = H.v4;
  if (lo) *(int4*)&lo[(size_t)idx * 8] = L.v4;
}

// ---------------------------------------------------------------------------
// Combined A split + W1 split + CSR degree count + w-tilde build, ONE dispatch.
// w-tilde: wt[h][i][f] = sum_d W[h,d,f] * a[h, i*HID+d]  (exact fp32) so that
// s_i[n] = x[n,:]. wt  — scores leave the MFMA GEMM entirely.
// ---------------------------------------------------------------------------
__global__ __launch_bounds__(256)
void split_frag2(const float* __restrict__ in1, unsigned short* __restrict__ hi1,
                 int R1, int K81, int total1, int nb1,
                 const float* __restrict__ in2, unsigned short* __restrict__ hi2,
                 int R2, int K82, int total2, int nb2,
                 const int* __restrict__ edst, int* __restrict__ deg, int E,
                 const float* __restrict__ av1, const float* __restrict__ W2p,
                 const float* __restrict__ av2,
                 float* __restrict__ wt1, float* __restrict__ wt2) {
  int b = (int)blockIdx.x;
  int tid = threadIdx.x;
  if (b < nb1) {
    int idx = b * 256 + tid;
    if (idx < total1) split_body(in1, hi1, nullptr, R1, K81, idx);
  } else if (b < nb1 + nb2) {
    int idx = (b - nb1) * 256 + tid;
    if (idx < total2) split_body(in2, hi2, nullptr, R2, K82, idx);
  } else {
    int nbE = (E + 255) / 256;
    int eb = b - nb1 - nb2;
    if (eb < nbE) {
      int e = eb * 256 + tid;
      if (e < E) atomicAdd(&deg[edst[e]], 1);
    } else {
      int wb = eb - nbE;
      if (wb < 32) {                      // wt1: 8192 outputs, 128-dots over W1
        int o = wb * 256 + tid;
        int f = o & 511, ii = (o >> 9) & 1, h = o >> 10;
        const float* Wp = in2 + (size_t)h * HID * N_FEAT + f;   // in2 == W1
        const float* ap = av1 + h * 2 * HID + ii * HID;
        float c0 = 0.f, c1 = 0.f;
        for (int d = 0; d < HID; d += 2) {
          c0 = fmaf(Wp[(size_t)d * N_FEAT], ap[d], c0);
          c1 = fmaf(Wp[(size_t)(d + 1) * N_FEAT], ap[d + 1], c1);
        }
        wt1[o] = c0 + c1;
      } else {                            // wt2: 2048 outputs over W2
        int o = (wb - 32) * 256 + tid;
        int f = o & 127, ii = (o >> 7) & 1, h = o >> 8;
        const float* Wp = W2p + (size_t)h * HID * HID + f;
        const float* ap = av2 + h * 2 * HID + ii * HID;
        float c0 = 0.f, c1 = 0.f;
        for (int d = 0; d < HID; d += 2) {
          c0 = fmaf(Wp[(size_t)d * HID], ap[d], c0);
          c1 = fmaf(Wp[(size_t)(d + 1) * HID], ap[d + 1], c1);
        }
        wt2[o] = c0 + c1;
      }
    }
  }
}

// ---------------------------------------------------------------------------
// Pure-bf16 MFMA GEMM, R4 restructure: 256 threads = 2x2 waves, 128x128
// output tile, BK=64.  vs R3: same iteration count but per-wave loads 24->16,
// occupancy 2->3 waves/SIMD (VGPR ~150), B re-read by 80 blocks/head instead
// of 160 (and L1-shared between the wave pair), per-XCD working set (A-slice
// 1.3MB + all-B 1MB, blk%8==mtile%8 affinity) fully L2-resident.  Epilogue is
// a bare hb store: scores moved to the exact w-tilde GEMV path.
// ---------------------------------------------------------------------------
__global__ __launch_bounds__(256, 3)
void gemm_frag(const unsigned short* __restrict__ Afh,
               const unsigned short* __restrict__ Bfh,
               unsigned short* __restrict__ hb,
               int M, int K) {
  int tid = threadIdx.x;
  int wave = tid >> 6, lane = tid & 63;
  int r = lane & 15, q = lane >> 4;
  int wr = wave >> 1, wc = wave & 1;

  int blk = blockIdx.x;
  int mtile = blk % 80;               // 80 tiles of 128 rows (10240 padded)
  int head = blk / 80;                // blk%8 == mtile%8 -> XCD A-affinity
  int m0 = mtile * 128;
  int K8 = K >> 3;

  const bf16x8* pA = (const bf16x8*)Afh;
  const bf16x8* pB = (const bf16x8*)Bfh;
  size_t rstep = (size_t)K8 * 16;
  size_t aidx = (size_t)((m0 >> 4) + wr * 4) * rstep + (size_t)q * 16 + r;
  size_t bidx = (size_t)(head * 8 + wc * 4) * rstep + (size_t)q * 16 + r;

  f32x4 acc[4][4] = {};

  for (int k0 = 0; k0 < K; k0 += 64, aidx += 128, bidx += 128) {
    bf16x8 a[8], b[8];
    #pragma unroll
    for (int i = 0; i < 4; ++i) {
      a[i]     = pA[aidx + i * rstep];
      b[i]     = pB[bidx + i * rstep];
      a[i + 4] = pA[aidx + i * rstep + 64];
      b[i + 4] = pB[bidx + i * rstep + 64];
    }
    #pragma unroll
    for (int i = 0; i < 4; ++i)
      #pragma unroll
      for (int j = 0; j < 4; ++j)
        acc[i][j] = __builtin_amdgcn_mfma_f32_16x16x32_bf16(a[i], b[j], acc[i][j], 0, 0, 0);
    #pragma unroll
    for (int i = 0; i < 4; ++i)
      #pragma unroll
      for (int j = 0; j < 4; ++j)
        acc[i][j] = __builtin_amdgcn_mfma_f32_16x16x32_bf16(a[i + 4], b[j + 4], acc[i][j], 0, 0, 0);
  }

  // epilogue: C/D layout col = r, row = q*4 + reg (per 16x16 frag)
  #pragma unroll
  for (int i = 0; i < 4; ++i)
    #pragma unroll
    for (int reg = 0; reg < 4; ++reg) {
      int row = m0 + wr * 64 + i * 16 + q * 4 + reg;
      if (row < M) {
        #pragma unroll
        for (int j = 0; j < 4; ++j)
          hb[((size_t)head * M + row) * HID + wc * 64 + j * 16 + r] =
              f2bf_rne(acc[i][j][reg]);
      }
    }
}

// ---------------------------------------------------------------------------
// CSR scan (block 0) + layer-1 score GEMV (blocks 1..): si/sj[h][n] = x[n].wt1.
// Fusing score blocks here fills the 255 CUs idle during the 1-block scan.
// ---------------------------------------------------------------------------
__global__ __launch_bounds__(1024)
void scan_score(const int* __restrict__ deg, int* __restrict__ off, int N,
                const float* __restrict__ x, const float* __restrict__ wt1,
                float* __restrict__ si, float* __restrict__ sj) {
  if (blockIdx.x == 0) {
    __shared__ int sums[1024];
    const int PER = 10;
    int tid = threadIdx.x;
    int base = tid * PER;
    int loc[PER];
    int run = 0;
    #pragma unroll
    for (int j = 0; j < PER; ++j) {
      int v = (base + j < N) ? deg[base + j] : 0;
      run += v;
      loc[j] = run;
    }
    sums[tid] = run;
    __syncthreads();
    for (int o = 1; o < 1024; o <<= 1) {
      int v = (tid >= o) ? sums[tid - o] : 0;
      __syncthreads();
      sums[tid] += v;
      __syncthreads();
    }
    int ex = sums[tid] - run;
    if (tid == 0) off[0] = 0;
    #pragma unroll
    for (int j = 0; j < PER; ++j)
      if (base + j < N) off[base + j + 1] = ex + loc[j];
    return;
  }
  // ---- score blocks: 64 rows each; wave = 4 rows x 16 lanes ----
  __shared__ float wl[8192];            // wt1 [16 t][512 f], 32 KB
  int tid = threadIdx.x;
  #pragma unroll
  for (int k = 0; k < 8; ++k) wl[tid + k * 1024] = wt1[tid + k * 1024];
  __syncthreads();
  int wv = tid >> 6, lane = tid & 63;
  int rr = lane >> 4, sl = lane & 15;
  int n = ((int)blockIdx.x - 1) * 64 + wv * 4 + rr;
  if (n >= N) return;
  const float* xp = x + (size_t)n * N_FEAT + sl * 4;
  float acc[16];
  #pragma unroll
  for (int t = 0; t < 16; ++t) acc[t] = 0.f;
  #pragma unroll
  for (int k = 0; k < 8; ++k) {
    float4 xv = *(const float4*)(xp + k * 64);
    #pragma unroll
    for (int t = 0; t < 16; ++t) {
      float4 w4 = *(const float4*)&wl[t * 512 + k * 64 + sl * 4];
      acc[t] = fmaf(xv.x, w4.x, fmaf(xv.y, w4.y, fmaf(xv.z, w4.z, fmaf(xv.w, w4.w, acc[t]))));
    }
  }
  #pragma unroll
  for (int o = 1; o <= 8; o <<= 1)
    #pragma unroll
    for (int t = 0; t < 16; ++t) acc[t] += __shfl_xor(acc[t], o);
  // lane sl owns t = sl (static-index select; all lanes hold all totals)
  float out = acc[0];
  #pragma unroll
  for (int t = 1; t < 16; ++t) out = (sl == t) ? acc[t] : out;
  int h = sl >> 1;
  if (sl & 1) sj[(size_t)h * N + n] = out;
  else        si[(size_t)h * N + n] = out;
}

__global__ void fill_kernel(const int* __restrict__ src, const int* __restrict__ dst,
                            const int* __restrict__ off, int* __restrict__ cursor,
                            int* __restrict__ ssrc, int E) {
  int e = blockIdx.x * blockDim.x + threadIdx.x;
  if (e < E) {
    int d = dst[e];
    int p = atomicAdd(&cursor[d], 1);
    ssrc[off[d] + p] = src[e];
  }
}

// ---------------------------------------------------------------------------
// FUSED softmax + aggregation: one wave = FOUR dst nodes (16 lanes per dst)
// of one head.  head = blk&7 (hb head-plane XCD L2 affinity).
// ---------------------------------------------------------------------------
__global__ __launch_bounds__(512)
void gat_aggregate8(const unsigned short* __restrict__ hb,
                    const float* __restrict__ si, const float* __restrict__ sj,
                    const int* __restrict__ off, const int* __restrict__ ssrc,
                    unsigned short* __restrict__ aggb, int N) {
  __shared__ int2 prs[8][4][32];   // [wave][group][edge-slot] (src, w)
  int head = blockIdx.x & 7;
  int wv = threadIdx.x >> 6;
  int lane = threadIdx.x & 63;
  int grp = lane >> 4;
  int sl = lane & 15;
  int n = (blockIdx.x >> 3) * 32 + wv * 4 + grp;
  const unsigned short* hbase = hb + (size_t)head * N * HID;
  const float* sjh = sj + (size_t)head * N;
  bool nv = n < N;
  int begin = 0, deg = 0;
  float s_i = 0.f;
  if (nv) {
    begin = off[n];
    deg = off[n + 1] - begin;
    s_i = si[(size_t)head * N + n];
  }

  // --- phase 1: per-lane edge scores, 2 slots (covers deg <= 32) ---
  int src0 = 0, src1 = 0;
  float sc0 = -INFINITY, sc1 = -INFINITY;
  if (sl < deg) {
    src0 = ssrc[begin + sl];
    float t = s_i + sjh[src0];
    sc0 = t > 0.f ? t : 0.01f * t;
  }
  if (16 + sl < deg) {
    src1 = ssrc[begin + 16 + sl];
    float t = s_i + sjh[src1];
    sc1 = t > 0.f ? t : 0.01f * t;
  }
  float m = fmaxf(sc0, sc1);
  for (int e2 = 32 + sl; e2 < deg; e2 += 16) {      // rare tail max
    int s = ssrc[begin + e2];
    float t = s_i + sjh[s];
    t = t > 0.f ? t : 0.01f * t;
    m = fmaxf(m, t);
  }
  #pragma unroll
  for (int o = 1; o <= 8; o <<= 1) m = fmaxf(m, __shfl_xor(m, o));

  float w0 = (sl < deg) ? __expf(sc0 - m) : 0.f;
  float w1 = (16 + sl < deg) ? __expf(sc1 - m) : 0.f;
  float den = w0 + w1;
  for (int e2 = 32 + sl; e2 < deg; e2 += 16) {      // rare tail denom
    int s = ssrc[begin + e2];
    float t = s_i + sjh[s];
    t = t > 0.f ? t : 0.01f * t;
    den += __expf(t - m);
  }
  #pragma unroll
  for (int o = 1; o <= 8; o <<= 1) den += __shfl_xor(den, o);

  // stage pairs (w=0 beyond deg; src=0 -> safe dummy gather)
  prs[wv][grp][sl] = make_int2(src0, __float_as_int(w0));
  prs[wv][grp][16 + sl] = make_int2(src1, __float_as_int(w1));
  // wave-synchronous LDS: ensure writes land + block compiler reorder.
  __asm__ volatile("s_waitcnt lgkmcnt(0)" ::: "memory");

  // --- gather: 16 lanes cover the 128-dim row, 4 edges in flight ---
  v2f a01 = {0.f, 0.f}, a23 = {0.f, 0.f}, a45 = {0.f, 0.f}, a67 = {0.f, 0.f};
  int dmin = deg < 32 ? deg : 32;
  for (int e0 = 0; e0 < dmin; e0 += 4) {            // slots e0..e0+3 <= 31 always init'd
    int2 p[4];
    #pragma unroll
    for (int u = 0; u < 4; ++u) p[u] = prs[wv][grp][e0 + u];
    int4 pv[4];
    #pragma unroll
    for (int u = 0; u < 4; ++u)
      pv[u] = *(const int4*)&hbase[(size_t)p[u].x * HID + sl * 8];
    #pragma unroll
    for (int u = 0; u < 4; ++u) {
      float w = __int_as_float(p[u].y);
      v2f w2 = {w, w};
      int4 q = pv[u];
      v2f t0 = {bf2f((unsigned)q.x & 0xffffu), __uint_as_float((unsigned)q.x & 0xffff0000u)};
      v2f t1 = {bf2f((unsigned)q.y & 0xffffu), __uint_as_float((unsigned)q.y & 0xffff0000u)};
      v2f t2 = {bf2f((unsigned)q.z & 0xffffu), __uint_as_float((unsigned)q.z & 0xffff0000u)};
      v2f t3 = {bf2f((unsigned)q.w & 0xffffu), __uint_as_float((unsigned)q.w & 0xffff0000u)};
      a01 += w2 * t0;                 // v_pk_fma_f32
      a23 += w2 * t1;
      a45 += w2 * t2;
      a67 += w2 * t3;
    }
  }
  // rare tail: deg > 32, recompute weight (uniform across the 16-lane group)
  for (int e2 = 32; e2 < deg; ++e2) {
    int s = ssrc[begin + e2];
    float t = s_i + sjh[s];
    t = t > 0.f ? t : 0.01f * t;
    float w = __expf(t - m);
    v2f w2 = {w, w};
    int4 q = *(const int4*)&hbase[(size_t)s * HID + sl * 8];
    v2f t0 = {bf2f((unsigned)q.x & 0xffffu), __uint_as_float((unsigned)q.x & 0xffff0000u)};
    v2f t1 = {bf2f((unsigned)q.y & 0xffffu), __uint_as_float((unsigned)q.y & 0xffff0000u)};
    v2f t2 = {bf2f((unsigned)q.z & 0xffffu), __uint_as_float((unsigned)q.z & 0xffff0000u)};
    v2f t3 = {bf2f((unsigned)q.w & 0xffffu), __uint_as_float((unsigned)q.w & 0xffff0000u)};
    a01 += w2 * t0; a23 += w2 * t1; a45 += w2 * t2; a67 += w2 * t3;
  }

  // --- epilogue: each lane owns 8 dims; all 64 lanes store ---
  if (nv) {
    float inv = den > 0.f ? 1.0f / den : 0.f;
    union { unsigned short u[8]; int4 v4; } P;
    P.u[0] = f2bf_rne(a01.x * inv); P.u[1] = f2bf_rne(a01.y * inv);
    P.u[2] = f2bf_rne(a23.x * inv); P.u[3] = f2bf_rne(a23.y * inv);
    P.u[4] = f2bf_rne(a45.x * inv); P.u[5] = f2bf_rne(a45.y * inv);
    P.u[6] = f2bf_rne(a67.x * inv); P.u[7] = f2bf_rne(a67.y * inv);
    *(int4*)&aggb[((size_t)head * N + n) * HID + sl * 8] = P.v4;
  }
}

// ---------------------------------------------------------------------------
// Head mean + ELU -> layer-2 A frags (bf16) + LAYER-2 SCORES (fp32 emb1 . wt2,
// block-complete reduction over the 16 col-chunks) + W2 split (blocks >= nbHM).
// ---------------------------------------------------------------------------
__global__ __launch_bounds__(256)
void headmean_frag_w2(const unsigned short* __restrict__ aggb,
                      unsigned short* __restrict__ hiA,
                      int N, int nbHM,
                      const float* __restrict__ W2, unsigned short* __restrict__ hiB,
                      int totalB,
                      const float* __restrict__ wt2,
                      float* __restrict__ si, float* __restrict__ sj) {
  if ((int)blockIdx.x >= nbHM) {
    int idx = (blockIdx.x - nbHM) * 256 + threadIdx.x;
    if (idx < totalB) split_body(W2, hiB, nullptr, HEADS * HID, 16, idx);
    return;
  }
  __shared__ float wl[2048];              // wt2 [16 t][128 f], 8 KB
  __shared__ float sred[16][16][17];      // [kq][r][t] (+1 pad), 17.4 KB
  int tid = threadIdx.x;
  #pragma unroll
  for (int k = 0; k < 8; ++k) wl[tid + k * 256] = wt2[tid + k * 256];
  __syncthreads();
  int idx = blockIdx.x * 256 + tid;       // (rb,kq,r), K8=16
  int r = idx & 15;
  int kq = (idx >> 4) & 15;
  int rb = idx >> 8;
  int n = rb * 16 + r;
  float s[8] = {0.f, 0.f, 0.f, 0.f, 0.f, 0.f, 0.f, 0.f};
  if (n < N) {
    #pragma unroll
    for (int hh = 0; hh < HEADS; ++hh) {
      int4 pv = *(const int4*)&aggb[((size_t)hh * N + n) * HID + kq * 8];
      s[0] += bf2f((unsigned)pv.x & 0xffffu);
      s[1] += __uint_as_float((unsigned)pv.x & 0xffff0000u);
      s[2] += bf2f((unsigned)pv.y & 0xffffu);
      s[3] += __uint_as_float((unsigned)pv.y & 0xffff0000u);
      s[4] += bf2f((unsigned)pv.z & 0xffffu);
      s[5] += __uint_as_float((unsigned)pv.z & 0xffff0000u);
      s[6] += bf2f((unsigned)pv.w & 0xffffu);
      s[7] += __uint_as_float((unsigned)pv.w & 0xffff0000u);
    }
  }
  float p[16];
  #pragma unroll
  for (int t = 0; t < 16; ++t) p[t] = 0.f;
  union { unsigned short u[8]; int4 v4; } H;
  #pragma unroll
  for (int e = 0; e < 8; ++e) {
    float v = s[e] * (1.0f / HEADS);
    v = v > 0.f ? v : (__expf(v) - 1.0f);   // ELU (fp32 emb1)
    #pragma unroll
    for (int t = 0; t < 16; ++t) p[t] = fmaf(v, wl[t * 128 + kq * 8 + e], p[t]);
    H.u[e] = f2bf_rne(v);
  }
  *(int4*)&hiA[(size_t)idx * 8] = H.v4;
  #pragma unroll
  for (int t = 0; t < 16; ++t) sred[kq][r][t] = p[t];
  __syncthreads();
  {
    int rr = tid >> 4, t = tid & 15;
    float sum = 0.f;
    #pragma unroll
    for (int k = 0; k < 16; ++k) sum += sred[k][rr][t];
    int nn = rb * 16 + rr;
    if (nn < N) {
      int h = t >> 1;
      if (t & 1) sj[(size_t)h * N + nn] = sum;
      else       si[(size_t)h * N + nn] = sum;
    }
  }
}

// ---------------------------------------------------------------------------
// Layer-2 tail: head mean + ELU + graph pooling fused (no emb2 materialized).
// ---------------------------------------------------------------------------
__global__ __launch_bounds__(256)
void headmean_pool(const unsigned short* __restrict__ aggb, float* __restrict__ g,
                   int N) {
  __shared__ float sm[16][128];
  int t = threadIdx.x;
  int nl = t >> 4, dg = t & 15;
  int n = blockIdx.x * 16 + nl;
  float v[8] = {0.f, 0.f, 0.f, 0.f, 0.f, 0.f, 0.f, 0.f};
  if (n < N) {
    #pragma unroll
    for (int hh = 0; hh < HEADS; ++hh) {
      int4 pv = *(const int4*)&aggb[((size_t)hh * N + n) * HID + dg * 8];
      v[0] += bf2f((unsigned)pv.x & 0xffffu);
      v[1] += __uint_as_float((unsigned)pv.x & 0xffff0000u);
      v[2] += bf2f((unsigned)pv.y & 0xffffu);
      v[3] += __uint_as_float((unsigned)pv.y & 0xffff0000u);
      v[4] += bf2f((unsigned)pv.z & 0xffffu);
      v[5] += __uint_as_float((unsigned)pv.z & 0xffff0000u);
      v[6] += bf2f((unsigned)pv.w & 0xffffu);
      v[7] += __uint_as_float((unsigned)pv.w & 0xffff0000u);
    }
    #pragma unroll
    for (int e = 0; e < 8; ++e) {
      float x = v[e] * (1.0f / HEADS);
      v[e] = x > 0.f ? x : (__expf(x) - 1.0f);   // ELU
    }
  }
  #pragma unroll
  for (int e = 0; e < 8; ++e) sm[nl][dg * 8 + e] = v[e];
  __syncthreads();
  if (t < 128) {
    float s = 0.f;
    #pragma unroll
    for (int nn = 0; nn < 16; ++nn) s += sm[nn][t];
    atomicAdd(&g[t], s);
  }
}

// ---------------------------------------------------------------------------
// LayerNorm + MLP head
// ---------------------------------------------------------------------------
__global__ __launch_bounds__(128)
void mlp_kernel(const float* __restrict__ g, const float* __restrict__ ln_g,
                const float* __restrict__ ln_b, const float* __restrict__ Wl1,
                const float* __restrict__ bl1, const float* __restrict__ Wl2,
                const float* __restrict__ bl2, const float* __restrict__ Wl3,
                const float* __restrict__ bl3, float* __restrict__ out, float invN) {
  __shared__ float red[128];
  __shared__ float gn[128];
  __shared__ float x1[64];
  __shared__ float x2[16];
  int t = threadIdx.x;
  float gg = g[t] * invN;
  red[t] = gg;
  __syncthreads();
  for (int o = 64; o > 0; o >>= 1) {
    if (t < o) red[t] += red[t + o];
    __syncthreads();
  }
  float mu = red[0] * (1.0f / HID);
  __syncthreads();
  float dv = gg - mu;
  red[t] = dv * dv;
  __syncthreads();
  for (int o = 64; o > 0; o >>= 1) {
    if (t < o) red[t] += red[t + o];
    __syncthreads();
  }
  float var = red[0] * (1.0f / HID);
  gn[t] = dv / sqrtf(var + 1e-5f) * ln_g[t] + ln_b[t];
  __syncthreads();
  if (t < 64) {
    float s = bl1[t];
    for (int k = 0; k < 128; ++k) s += Wl1[t * 128 + k] * gn[k];
    x1[t] = s > 0.f ? s : 0.01f * s;
  }
  __syncthreads();
  if (t < 16) {
    float s = bl2[t];
    for (int k = 0; k < 64; ++k) s += Wl2[t * 64 + k] * x1[k];
    x2[t] = s > 0.f ? s : 0.01f * s;
  }
  __syncthreads();
  if (t < 16) {
    float s = bl3[t];
    for (int k = 0; k < 16; ++k) s += Wl3[t * 16 + k] * x2[k];
    out[t] = s > 0.f ? s : 0.f;
  }
}

// ---------------------------------------------------------------------------
extern "C" void kernel_launch(void* const* d_in, const int* in_sizes, int n_in,
                              void* d_out, int out_size, void* d_ws, size_t ws_size,
                              hipStream_t stream) {
  const float* x    = (const float*)d_in[0];
  const int*   esrc = (const int*)d_in[1];
  const int*   edst = (const int*)d_in[2];
  const float* W1   = (const float*)d_in[3];
  const float* a1   = (const float*)d_in[4];
  const float* W2   = (const float*)d_in[5];
  const float* a2   = (const float*)d_in[6];
  const float* ln_g = (const float*)d_in[7];
  const float* ln_b = (const float*)d_in[8];
  const float* Wl1  = (const float*)d_in[9];
  const float* bl1  = (const float*)d_in[10];
  const float* Wl2  = (const float*)d_in[11];
  const float* bl2  = (const float*)d_in[12];
  const float* Wl3  = (const float*)d_in[13];
  const float* bl3  = (const float*)d_in[14];
  float* out = (float*)d_out;

  const int RBPAD = 640;  // row-blocks padded (10240 rows) for in-bounds frags

  // workspace carve-up (g, deg, cur contiguous -> one memset)
  unsigned short* aggb = (unsigned short*)d_ws;                 // 20.5 MB
  float* si   = (float*)(aggb + (size_t)N_NODES * HEADS * HID); // 80,000
  float* sj   = si + N_NODES * HEADS;                           // 80,000
  float* g    = sj + N_NODES * HEADS;                           // 128
  int*   deg  = (int*)(g + 128);                                // 10,000
  int*   cur  = deg + N_NODES;                                  // 10,000
  int*   off  = cur + N_NODES;                                  // 10,001 -> pad 10,004
  int*   ssrc = off + 10004;                                    // 160,000
  unsigned short* Afh = (unsigned short*)(ssrc + N_EDGES);      // 10.5 MB frags
  float* wt1 = (float*)(Afh + (size_t)RBPAD * 64 * 128);        // (old Afl region)
  float* wt2 = wt1 + 8192;
  unsigned short* Bfh = (unsigned short*)(wt1 + (size_t)RBPAD * 64 * 64); // old slot
  unsigned short* hb  = Bfh + (size_t)2 * 64 * 64 * 128;        // 20.5 MB (old slot)

  // zero g + deg + cur in ONE memset (contiguous)
  hipMemsetAsync(g, 0, 128 * sizeof(float) + 2 * N_NODES * sizeof(int), stream);

  int gemmGrid = 80 * HEADS;                      // 640 blocks of 256 threads
  int aggGrid = ((N_NODES + 31) / 32) * 8;        // 2504 blocks: 32 dst x 1 head each

  // ---- Layer 1: A-split + W1-split + CSR count + wt1/wt2 in one dispatch ----
  {
    int totalA = RBPAD * 64 * 16;             // K8=64
    int nbA = (totalA + 255) / 256;           // 2560
    int totalB = 64 * 64 * 16;                // W1: 1024 rows, K8=64
    int nbB = (totalB + 255) / 256;           // 256
    int nbE = (N_EDGES + 255) / 256;          // 625
    int nbW = 40;                             // 32 wt1 + 8 wt2
    split_frag2<<<nbA + nbB + nbE + nbW, 256, 0, stream>>>(
        x, Afh, N_NODES, 64, totalA, nbA,
        W1, Bfh, HEADS * HID, 64, totalB, nbB,
        edst, deg, N_EDGES,
        a1, W2, a2, wt1, wt2);
  }
  // CSR scan (1 block) + layer-1 score GEMV (157 blocks) fused
  scan_score<<<1 + (N_NODES + 63) / 64, 1024, 0, stream>>>(deg, off, N_NODES,
                                                           x, wt1, si, sj);
  fill_kernel<<<(N_EDGES + 255) / 256, 256, 0, stream>>>(esrc, edst, off, cur, ssrc, N_EDGES);

  gemm_frag<<<gemmGrid, 256, 0, stream>>>(Afh, Bfh, hb, N_NODES, N_FEAT);
  gat_aggregate8<<<aggGrid, 512, 0, stream>>>(hb, si, sj, off, ssrc, aggb, N_NODES);
  {
    int nbHM = (N_NODES + 15) / 16;                       // 625
    int totalB = 64 * 16 * 16;                            // W2: 1024 rows, K8=16
    int nbB = (totalB + 255) / 256;                       // 64
    headmean_frag_w2<<<nbHM + nbB, 256, 0, stream>>>(aggb, Afh, N_NODES, nbHM,
                                                     W2, Bfh, totalB,
                                                     wt2, si, sj);
  }

  // ---- Layer 2 ----
  gemm_frag<<<gemmGrid, 256, 0, stream>>>(Afh, Bfh, hb, N_NODES, HID);
  gat_aggregate8<<<aggGrid, 512, 0, stream>>>(hb, si, sj, off, ssrc, aggb, N_NODES);

  // ---- fused head-mean + pooling + MLP head ----
  headmean_pool<<<(N_NODES + 15) / 16, 256, 0, stream>>>(aggb, g, N_NODES);
  mlp_kernel<<<1, 128, 0, stream>>>(g, ln_g, ln_b, Wl1, bl1, Wl2, bl2, Wl3, bl3,
                                    out, 1.0f / N_NODES);
}

// Round 7
// 242.054 us; speedup vs baseline: 1.0398x; 1.0398x over previous
//
#include <hip/hip_runtime.h>
#include <math.h>

#define N_NODES 10000
#define N_EDGES 160000
#define N_FEAT  512
#define HEADS   8
#define HID     128

typedef __attribute__((ext_vector_type(8))) short bf16x8;
typedef __attribute__((ext_vector_type(4))) float f32x4;
typedef __attribute__((ext_vector_type(2))) float v2f;

// ---------------------------------------------------------------------------
// fp32 <-> bf16 helpers
// ---------------------------------------------------------------------------
__device__ inline unsigned short f2bf_rne(float f) {
  unsigned int u = __float_as_uint(f);
  unsigned int r = u + 0x7fffu + ((u >> 16) & 1u);
  return (unsigned short)(r >> 16);
}
__device__ inline float bf2f(unsigned int b) {
  return __uint_as_float(b << 16);
}

// ---------------------------------------------------------------------------
// split body: fp32 [R][K] -> bf16 in MFMA-fragment-major layout (hi only).
// ---------------------------------------------------------------------------
__device__ inline void split_body(const float* __restrict__ in,
                                  unsigned short* __restrict__ hi,
                                  int R, int K8, int idx) {
  int r = idx & 15;
  int t = idx >> 4;
  int kq = t % K8;
  int rb = t / K8;
  int row = rb * 16 + r;
  float v[8] = {0.f, 0.f, 0.f, 0.f, 0.f, 0.f, 0.f, 0.f};
  if (row < R) {
    const float* p = in + (size_t)row * (K8 * 8) + kq * 8;
    float4 a = *(const float4*)p;
    float4 b = *(const float4*)(p + 4);
    v[0] = a.x; v[1] = a.y; v[2] = a.z; v[3] = a.w;
    v[4] = b.x; v[5] = b.y; v[6] = b.z; v[7] = b.w;
  }
  union { unsigned short u[8]; int4 v4; } H;
  #pragma unroll
  for (int e = 0; e < 8; ++e) H.u[e] = f2bf_rne(v[e]);
  *(int4*)&hi[(size_t)idx * 8] = H.v4;
}

// ---------------------------------------------------------------------------
// ONE dispatch: A split + W1 split + W2 split + bucket-CSR build + w-tilde.
// Bucket CSR: slots[n][32] filled via atomicAdd(deg) — Poisson(16) so
// P(deg>32)~1e-4; overflow edges go to a bounded (dst,src) list scanned by
// the aggregate's rare tail.  Replaces the scan+fill dispatches entirely.
// R6 hardening: ovf write is bounds-guarded (defensive vs any replay
// without the preceding memset).
// ---------------------------------------------------------------------------
__global__ __launch_bounds__(256)
void split_frag2(const float* __restrict__ in1, unsigned short* __restrict__ hi1,
                 int R1, int K81, int total1, int nb1,
                 const float* __restrict__ in2, unsigned short* __restrict__ hi2,
                 int R2, int K82, int total2, int nb2,
                 const float* __restrict__ W2p, unsigned short* __restrict__ hi3,
                 int total3, int nb3,
                 const int* __restrict__ esrc, const int* __restrict__ edst,
                 int* __restrict__ deg, int* __restrict__ slots,
                 int2* __restrict__ ovf, int* __restrict__ cnt, int E,
                 const float* __restrict__ av1, const float* __restrict__ av2,
                 float* __restrict__ wt1, float* __restrict__ wt2) {
  int b = (int)blockIdx.x;
  int tid = threadIdx.x;
  if (b < nb1) {
    int idx = b * 256 + tid;
    if (idx < total1) split_body(in1, hi1, R1, K81, idx);
  } else if (b < nb1 + nb2) {
    int idx = (b - nb1) * 256 + tid;
    if (idx < total2) split_body(in2, hi2, R2, K82, idx);
  } else if (b < nb1 + nb2 + nb3) {
    int idx = (b - nb1 - nb2) * 256 + tid;
    if (idx < total3) split_body(W2p, hi3, HEADS * HID, 16, idx);
  } else {
    int nbE = (E + 255) / 256;
    int eb = b - nb1 - nb2 - nb3;
    if (eb < nbE) {
      int e = eb * 256 + tid;
      if (e < E) {
        int d = edst[e], s = esrc[e];
        int p = atomicAdd(&deg[d], 1);
        if (p < 32) {
          slots[d * 32 + p] = s;
        } else {
          int q = atomicAdd(&cnt[1], 1);
          if (q < E) ovf[q] = make_int2(d, s);   // bounded (defensive)
        }
      }
    } else {
      int wb = eb - nbE;
      if (wb < 32) {                      // wt1: 8192 outputs, 128-dots over W1
        int o = wb * 256 + tid;
        int f = o & 511, ii = (o >> 9) & 1, h = o >> 10;
        const float* Wp = in2 + (size_t)h * HID * N_FEAT + f;   // in2 == W1
        const float* ap = av1 + h * 2 * HID + ii * HID;
        float c0 = 0.f, c1 = 0.f;
        for (int d = 0; d < HID; d += 2) {
          c0 = fmaf(Wp[(size_t)d * N_FEAT], ap[d], c0);
          c1 = fmaf(Wp[(size_t)(d + 1) * N_FEAT], ap[d + 1], c1);
        }
        wt1[o] = c0 + c1;
      } else {                            // wt2: 2048 outputs over W2
        int o = (wb - 32) * 256 + tid;
        int f = o & 127, ii = (o >> 7) & 1, h = o >> 8;
        const float* Wp = W2p + (size_t)h * HID * HID + f;
        const float* ap = av2 + h * 2 * HID + ii * HID;
        float c0 = 0.f, c1 = 0.f;
        for (int d = 0; d < HID; d += 2) {
          c0 = fmaf(Wp[(size_t)d * HID], ap[d], c0);
          c1 = fmaf(Wp[(size_t)(d + 1) * HID], ap[d + 1], c1);
        }
        wt2[o] = c0 + c1;
      }
    }
  }
}

// ---------------------------------------------------------------------------
// Pure-bf16 MFMA GEMM (128x128 tile, 2x2 waves, BK=64) + FUSED layer-1 score
// GEMV blocks (blocks >= nbGemm): si/sj = x . wt1, exact fp32.  Score output
// is first consumed by the NEXT dispatch (agg L1) — safe in-dispatch fusion.
// ---------------------------------------------------------------------------
__global__ __launch_bounds__(256, 3)
void gemm_score(const unsigned short* __restrict__ Afh,
                const unsigned short* __restrict__ Bfh,
                unsigned short* __restrict__ hb,
                int M, int K, int nbGemm,
                const float* __restrict__ x, const float* __restrict__ wt1,
                float* __restrict__ si, float* __restrict__ sj, int N) {
  int tid = threadIdx.x;
  if ((int)blockIdx.x >= nbGemm) {
    // ---- score blocks: 16 rows each; wave = 4 rows x 16 lanes ----
    __shared__ float wl[8192];            // wt1 [16 t][512 f], 32 KB
    #pragma unroll
    for (int k = 0; k < 32; ++k) wl[tid + k * 256] = wt1[tid + k * 256];
    __syncthreads();
    int wv = tid >> 6, lane = tid & 63;
    int rr = lane >> 4, sl = lane & 15;
    int n = ((int)blockIdx.x - nbGemm) * 16 + wv * 4 + rr;
    if (n >= N) return;
    const float* xp = x + (size_t)n * N_FEAT + sl * 4;
    float acc[16];
    #pragma unroll
    for (int t = 0; t < 16; ++t) acc[t] = 0.f;
    #pragma unroll
    for (int k = 0; k < 8; ++k) {
      float4 xv = *(const float4*)(xp + k * 64);
      #pragma unroll
      for (int t = 0; t < 16; ++t) {
        float4 w4 = *(const float4*)&wl[t * 512 + k * 64 + sl * 4];
        acc[t] = fmaf(xv.x, w4.x, fmaf(xv.y, w4.y, fmaf(xv.z, w4.z, fmaf(xv.w, w4.w, acc[t]))));
      }
    }
    #pragma unroll
    for (int o = 1; o <= 8; o <<= 1)
      #pragma unroll
      for (int t = 0; t < 16; ++t) acc[t] += __shfl_xor(acc[t], o);
    float outv = acc[0];
    #pragma unroll
    for (int t = 1; t < 16; ++t) outv = (sl == t) ? acc[t] : outv;
    int h = sl >> 1;
    if (sl & 1) sj[(size_t)h * N + n] = outv;
    else        si[(size_t)h * N + n] = outv;
    return;
  }

  int wave = tid >> 6, lane = tid & 63;
  int r = lane & 15, q = lane >> 4;
  int wr = wave >> 1, wc = wave & 1;

  int blk = blockIdx.x;
  int mtile = blk % 80;               // 80 tiles of 128 rows (10240 padded)
  int head = blk / 80;                // blk%8 == mtile%8 -> XCD A-affinity
  int m0 = mtile * 128;
  int K8 = K >> 3;

  const bf16x8* pA = (const bf16x8*)Afh;
  const bf16x8* pB = (const bf16x8*)Bfh;
  size_t rstep = (size_t)K8 * 16;
  size_t aidx = (size_t)((m0 >> 4) + wr * 4) * rstep + (size_t)q * 16 + r;
  size_t bidx = (size_t)(head * 8 + wc * 4) * rstep + (size_t)q * 16 + r;

  f32x4 acc[4][4] = {};

  for (int k0 = 0; k0 < K; k0 += 64, aidx += 128, bidx += 128) {
    bf16x8 a[8], b[8];
    #pragma unroll
    for (int i = 0; i < 4; ++i) {
      a[i]     = pA[aidx + i * rstep];
      b[i]     = pB[bidx + i * rstep];
      a[i + 4] = pA[aidx + i * rstep + 64];
      b[i + 4] = pB[bidx + i * rstep + 64];
    }
    #pragma unroll
    for (int i = 0; i < 4; ++i)
      #pragma unroll
      for (int j = 0; j < 4; ++j)
        acc[i][j] = __builtin_amdgcn_mfma_f32_16x16x32_bf16(a[i], b[j], acc[i][j], 0, 0, 0);
    #pragma unroll
    for (int i = 0; i < 4; ++i)
      #pragma unroll
      for (int j = 0; j < 4; ++j)
        acc[i][j] = __builtin_amdgcn_mfma_f32_16x16x32_bf16(a[i + 4], b[j + 4], acc[i][j], 0, 0, 0);
  }

  // epilogue: C/D layout col = r, row = q*4 + reg (per 16x16 frag)
  #pragma unroll
  for (int i = 0; i < 4; ++i)
    #pragma unroll
    for (int reg = 0; reg < 4; ++reg) {
      int row = m0 + wr * 64 + i * 16 + q * 4 + reg;
      if (row < M) {
        #pragma unroll
        for (int j = 0; j < 4; ++j)
          hb[((size_t)head * M + row) * HID + wc * 64 + j * 16 + r] =
              f2bf_rne(acc[i][j][reg]);
      }
    }
}

// ---------------------------------------------------------------------------
// FUSED softmax + aggregation on the bucket CSR: one wave = FOUR dst nodes
// (16 lanes per dst) of one head.  Gather unrolled x2 (8 row-gathers in
// flight — agg is L2-latency-bound, VGPR headroom is large).  deg>32 tail
// scans the tiny overflow list (oc clamped defensively).
// ---------------------------------------------------------------------------
__global__ __launch_bounds__(512)
void gat_aggregate9(const unsigned short* __restrict__ hb,
                    const float* __restrict__ si, const float* __restrict__ sj,
                    const int* __restrict__ deg, const int* __restrict__ slots,
                    const int2* __restrict__ ovf, const int* __restrict__ cnt,
                    unsigned short* __restrict__ aggb, int N) {
  __shared__ int2 prs[8][4][32];   // [wave][group][edge-slot] (src, w)
  int head = blockIdx.x & 7;
  int wv = threadIdx.x >> 6;
  int lane = threadIdx.x & 63;
  int grp = lane >> 4;
  int sl = lane & 15;
  int n = (blockIdx.x >> 3) * 32 + wv * 4 + grp;
  const unsigned short* hbase = hb + (size_t)head * N * HID;
  const float* sjh = sj + (size_t)head * N;
  bool nv = n < N;
  int dg = 0;
  float s_i = 0.f;
  if (nv) {
    dg = deg[n];
    s_i = si[(size_t)head * N + n];
  }
  int sbase = n * 32;

  // --- phase 1: per-lane edge scores, 2 slots (covers deg <= 32) ---
  int src0 = 0, src1 = 0;
  float sc0 = -INFINITY, sc1 = -INFINITY;
  if (sl < dg) {
    src0 = slots[sbase + sl];
    float t = s_i + sjh[src0];
    sc0 = t > 0.f ? t : 0.01f * t;
  }
  if (16 + sl < dg) {
    src1 = slots[sbase + 16 + sl];
    float t = s_i + sjh[src1];
    sc1 = t > 0.f ? t : 0.01f * t;
  }
  float m = fmaxf(sc0, sc1);
  int oc = 0;
  if (dg > 32) {                    // rare overflow tail: max
    oc = cnt[1];
    if (oc > N_EDGES) oc = N_EDGES; // defensive clamp
    for (int e2 = sl; e2 < oc; e2 += 16) {
      int2 pe = ovf[e2];
      if (pe.x == n) {
        float t = s_i + sjh[pe.y];
        t = t > 0.f ? t : 0.01f * t;
        m = fmaxf(m, t);
      }
    }
  }
  #pragma unroll
  for (int o = 1; o <= 8; o <<= 1) m = fmaxf(m, __shfl_xor(m, o));

  float w0 = (sl < dg) ? __expf(sc0 - m) : 0.f;
  float w1 = (16 + sl < dg) ? __expf(sc1 - m) : 0.f;
  float den = w0 + w1;
  if (dg > 32) {                    // rare overflow tail: denom
    for (int e2 = sl; e2 < oc; e2 += 16) {
      int2 pe = ovf[e2];
      if (pe.x == n) {
        float t = s_i + sjh[pe.y];
        t = t > 0.f ? t : 0.01f * t;
        den += __expf(t - m);
      }
    }
  }
  #pragma unroll
  for (int o = 1; o <= 8; o <<= 1) den += __shfl_xor(den, o);

  // stage pairs (w=0 beyond deg; src=0 -> safe dummy gather)
  prs[wv][grp][sl] = make_int2(src0, __float_as_int(w0));
  prs[wv][grp][16 + sl] = make_int2(src1, __float_as_int(w1));
  // wave-synchronous LDS: ensure writes land + block compiler reorder.
  __asm__ volatile("s_waitcnt lgkmcnt(0)" ::: "memory");

  // --- gather: 16 lanes cover the 128-dim row, 8 edges in flight ---
  v2f a01 = {0.f, 0.f}, a23 = {0.f, 0.f}, a45 = {0.f, 0.f}, a67 = {0.f, 0.f};
  int dmin = dg < 32 ? dg : 32;
  for (int e0 = 0; e0 < dmin; e0 += 8) {            // slots e0..e0+7 <= 31 always init'd
    int2 p[8];
    #pragma unroll
    for (int u = 0; u < 8; ++u) p[u] = prs[wv][grp][e0 + u];
    int4 pv[8];
    #pragma unroll
    for (int u = 0; u < 8; ++u)
      pv[u] = *(const int4*)&hbase[(size_t)p[u].x * HID + sl * 8];
    #pragma unroll
    for (int u = 0; u < 8; ++u) {
      float w = __int_as_float(p[u].y);
      v2f w2 = {w, w};
      int4 q = pv[u];
      v2f t0 = {bf2f((unsigned)q.x & 0xffffu), __uint_as_float((unsigned)q.x & 0xffff0000u)};
      v2f t1 = {bf2f((unsigned)q.y & 0xffffu), __uint_as_float((unsigned)q.y & 0xffff0000u)};
      v2f t2 = {bf2f((unsigned)q.z & 0xffffu), __uint_as_float((unsigned)q.z & 0xffff0000u)};
      v2f t3 = {bf2f((unsigned)q.w & 0xffffu), __uint_as_float((unsigned)q.w & 0xffff0000u)};
      a01 += w2 * t0;                 // v_pk_fma_f32
      a23 += w2 * t1;
      a45 += w2 * t2;
      a67 += w2 * t3;
    }
  }
  // rare tail: deg > 32, weights recomputed from the overflow list
  if (dg > 32) {
    for (int e2 = 0; e2 < oc; ++e2) {
      int2 pe = ovf[e2];
      if (pe.x != n) continue;
      float t = s_i + sjh[pe.y];
      t = t > 0.f ? t : 0.01f * t;
      float w = __expf(t - m);
      v2f w2 = {w, w};
      int4 q = *(const int4*)&hbase[(size_t)pe.y * HID + sl * 8];
      v2f t0 = {bf2f((unsigned)q.x & 0xffffu), __uint_as_float((unsigned)q.x & 0xffff0000u)};
      v2f t1 = {bf2f((unsigned)q.y & 0xffffu), __uint_as_float((unsigned)q.y & 0xffff0000u)};
      v2f t2 = {bf2f((unsigned)q.z & 0xffffu), __uint_as_float((unsigned)q.z & 0xffff0000u)};
      v2f t3 = {bf2f((unsigned)q.w & 0xffffu), __uint_as_float((unsigned)q.w & 0xffff0000u)};
      a01 += w2 * t0; a23 += w2 * t1; a45 += w2 * t2; a67 += w2 * t3;
    }
  }

  // --- epilogue: each lane owns 8 dims; all 64 lanes store ---
  if (nv) {
    float inv = den > 0.f ? 1.0f / den : 0.f;
    union { unsigned short u[8]; int4 v4; } P;
    P.u[0] = f2bf_rne(a01.x * inv); P.u[1] = f2bf_rne(a01.y * inv);
    P.u[2] = f2bf_rne(a23.x * inv); P.u[3] = f2bf_rne(a23.y * inv);
    P.u[4] = f2bf_rne(a45.x * inv); P.u[5] = f2bf_rne(a45.y * inv);
    P.u[6] = f2bf_rne(a67.x * inv); P.u[7] = f2bf_rne(a67.y * inv);
    *(int4*)&aggb[((size_t)head * N + n) * HID + sl * 8] = P.v4;
  }
}

// ---------------------------------------------------------------------------
// Head mean + ELU -> layer-2 A frags (bf16) + LAYER-2 SCORES (fp32 emb1 . wt2,
// block-complete reduction over the 16 col-chunks).
// ---------------------------------------------------------------------------
__global__ __launch_bounds__(256)
void headmean_frag2(const unsigned short* __restrict__ aggb,
                    unsigned short* __restrict__ hiA, int N,
                    const float* __restrict__ wt2,
                    float* __restrict__ si, float* __restrict__ sj) {
  __shared__ float wl[2048];              // wt2 [16 t][128 f], 8 KB
  __shared__ float sred[16][16][17];      // [kq][r][t] (+1 pad), 17.4 KB
  int tid = threadIdx.x;
  #pragma unroll
  for (int k = 0; k < 8; ++k) wl[tid + k * 256] = wt2[tid + k * 256];
  __syncthreads();
  int idx = blockIdx.x * 256 + tid;       // (rb,kq,r), K8=16
  int r = idx & 15;
  int kq = (idx >> 4) & 15;
  int rb = idx >> 8;
  int n = rb * 16 + r;
  float s[8] = {0.f, 0.f, 0.f, 0.f, 0.f, 0.f, 0.f, 0.f};
  if (n < N) {
    #pragma unroll
    for (int hh = 0; hh < HEADS; ++hh) {
      int4 pv = *(const int4*)&aggb[((size_t)hh * N + n) * HID + kq * 8];
      s[0] += bf2f((unsigned)pv.x & 0xffffu);
      s[1] += __uint_as_float((unsigned)pv.x & 0xffff0000u);
      s[2] += bf2f((unsigned)pv.y & 0xffffu);
      s[3] += __uint_as_float((unsigned)pv.y & 0xffff0000u);
      s[4] += bf2f((unsigned)pv.z & 0xffffu);
      s[5] += __uint_as_float((unsigned)pv.z & 0xffff0000u);
      s[6] += bf2f((unsigned)pv.w & 0xffffu);
      s[7] += __uint_as_float((unsigned)pv.w & 0xffff0000u);
    }
  }
  float p[16];
  #pragma unroll
  for (int t = 0; t < 16; ++t) p[t] = 0.f;
  union { unsigned short u[8]; int4 v4; } H;
  #pragma unroll
  for (int e = 0; e < 8; ++e) {
    float v = s[e] * (1.0f / HEADS);
    v = v > 0.f ? v : (__expf(v) - 1.0f);   // ELU (fp32 emb1)
    #pragma unroll
    for (int t = 0; t < 16; ++t) p[t] = fmaf(v, wl[t * 128 + kq * 8 + e], p[t]);
    H.u[e] = f2bf_rne(v);
  }
  *(int4*)&hiA[(size_t)idx * 8] = H.v4;
  #pragma unroll
  for (int t = 0; t < 16; ++t) sred[kq][r][t] = p[t];
  __syncthreads();
  {
    int rr = tid >> 4, t = tid & 15;
    float sum = 0.f;
    #pragma unroll
    for (int k = 0; k < 16; ++k) sum += sred[k][rr][t];
    int nn = rb * 16 + rr;
    if (nn < N) {
      int h = t >> 1;
      if (t & 1) sj[(size_t)h * N + nn] = sum;
      else       si[(size_t)h * N + nn] = sum;
    }
  }
}

// ---------------------------------------------------------------------------
// Layer-2 tail: head mean + ELU + graph pooling (R4-proven separate dispatch).
// ---------------------------------------------------------------------------
__global__ __launch_bounds__(256)
void headmean_pool(const unsigned short* __restrict__ aggb, float* __restrict__ g,
                   int N) {
  __shared__ float sm[16][128];
  int t = threadIdx.x;
  int nl = t >> 4, dg = t & 15;
  int n = blockIdx.x * 16 + nl;
  float v[8] = {0.f, 0.f, 0.f, 0.f, 0.f, 0.f, 0.f, 0.f};
  if (n < N) {
    #pragma unroll
    for (int hh = 0; hh < HEADS; ++hh) {
      int4 pv = *(const int4*)&aggb[((size_t)hh * N + n) * HID + dg * 8];
      v[0] += bf2f((unsigned)pv.x & 0xffffu);
      v[1] += __uint_as_float((unsigned)pv.x & 0xffff0000u);
      v[2] += bf2f((unsigned)pv.y & 0xffffu);
      v[3] += __uint_as_float((unsigned)pv.y & 0xffff0000u);
      v[4] += bf2f((unsigned)pv.z & 0xffffu);
      v[5] += __uint_as_float((unsigned)pv.z & 0xffff0000u);
      v[6] += bf2f((unsigned)pv.w & 0xffffu);
      v[7] += __uint_as_float((unsigned)pv.w & 0xffff0000u);
    }
    #pragma unroll
    for (int e = 0; e < 8; ++e) {
      float x = v[e] * (1.0f / HEADS);
      v[e] = x > 0.f ? x : (__expf(x) - 1.0f);   // ELU
    }
  }
  #pragma unroll
  for (int e = 0; e < 8; ++e) sm[nl][dg * 8 + e] = v[e];
  __syncthreads();
  if (t < 128) {
    float s = 0.f;
    #pragma unroll
    for (int nn = 0; nn < 16; ++nn) s += sm[nn][t];
    atomicAdd(&g[t], s);
  }
}

// ---------------------------------------------------------------------------
// LayerNorm + MLP head
// ---------------------------------------------------------------------------
__global__ __launch_bounds__(128)
void mlp_kernel(const float* __restrict__ g, const float* __restrict__ ln_g,
                const float* __restrict__ ln_b, const float* __restrict__ Wl1,
                const float* __restrict__ bl1, const float* __restrict__ Wl2,
                const float* __restrict__ bl2, const float* __restrict__ Wl3,
                const float* __restrict__ bl3, float* __restrict__ out, float invN) {
  __shared__ float red[128];
  __shared__ float gn[128];
  __shared__ float x1[64];
  __shared__ float x2[16];
  int t = threadIdx.x;
  float gg = g[t] * invN;
  red[t] = gg;
  __syncthreads();
  for (int o = 64; o > 0; o >>= 1) {
    if (t < o) red[t] += red[t + o];
    __syncthreads();
  }
  float mu = red[0] * (1.0f / HID);
  __syncthreads();
  float dv = gg - mu;
  red[t] = dv * dv;
  __syncthreads();
  for (int o = 64; o > 0; o >>= 1) {
    if (t < o) red[t] += red[t + o];
    __syncthreads();
  }
  float var = red[0] * (1.0f / HID);
  gn[t] = dv / sqrtf(var + 1e-5f) * ln_g[t] + ln_b[t];
  __syncthreads();
  if (t < 64) {
    float s = bl1[t];
    for (int k = 0; k < 128; ++k) s += Wl1[t * 128 + k] * gn[k];
    x1[t] = s > 0.f ? s : 0.01f * s;
  }
  __syncthreads();
  if (t < 16) {
    float s = bl2[t];
    for (int k = 0; k < 64; ++k) s += Wl2[t * 64 + k] * x1[k];
    x2[t] = s > 0.f ? s : 0.01f * s;
  }
  __syncthreads();
  if (t < 16) {
    float s = bl3[t];
    for (int k = 0; k < 16; ++k) s += Wl3[t * 16 + k] * x2[k];
    out[t] = s > 0.f ? s : 0.f;
  }
}

// ---------------------------------------------------------------------------
extern "C" void kernel_launch(void* const* d_in, const int* in_sizes, int n_in,
                              void* d_out, int out_size, void* d_ws, size_t ws_size,
                              hipStream_t stream) {
  const float* x    = (const float*)d_in[0];
  const int*   esrc = (const int*)d_in[1];
  const int*   edst = (const int*)d_in[2];
  const float* W1   = (const float*)d_in[3];
  const float* a1   = (const float*)d_in[4];
  const float* W2   = (const float*)d_in[5];
  const float* a2   = (const float*)d_in[6];
  const float* ln_g = (const float*)d_in[7];
  const float* ln_b = (const float*)d_in[8];
  const float* Wl1  = (const float*)d_in[9];
  const float* bl1  = (const float*)d_in[10];
  const float* Wl2  = (const float*)d_in[11];
  const float* bl2  = (const float*)d_in[12];
  const float* Wl3  = (const float*)d_in[13];
  const float* bl3  = (const float*)d_in[14];
  float* out = (float*)d_out;

  const int RBPAD = 640;  // row-blocks padded (10240 rows) for in-bounds frags

  // workspace carve-up (g, deg, cnt contiguous -> one memset)
  unsigned short* aggb = (unsigned short*)d_ws;                 // 20.5 MB
  float* si   = (float*)(aggb + (size_t)N_NODES * HEADS * HID); // 80,000
  float* sj   = si + N_NODES * HEADS;                           // 80,000
  float* g    = sj + N_NODES * HEADS;                           // 128
  int*   deg  = (int*)(g + 128);                                // 10,000
  int*   cnt  = deg + N_NODES;                                  // 4 (spare, ovf)
  int*   slots= cnt + 4;                                        // 320,000
  int2*  ovf  = (int2*)(slots + (size_t)N_NODES * 32);          // worst-case E
  float* wt1  = (float*)(ovf + N_EDGES);                        // 8192
  float* wt2  = wt1 + 8192;                                     // 2048
  unsigned short* Afh  = (unsigned short*)(wt2 + 2048);         // 10.5 MB
  unsigned short* Bfh  = Afh + (size_t)RBPAD * 64 * 128;        // W1 frags 1 MB
  unsigned short* Bfh2 = Bfh + (size_t)1024 * 512;              // W2 frags 256 KB
  unsigned short* hb   = Bfh2 + (size_t)1024 * 128;             // 20.5 MB

  // zero g + deg + cnt in ONE memset (contiguous)
  hipMemsetAsync(g, 0, 128 * sizeof(float) + (N_NODES + 4) * sizeof(int), stream);

  int gemmGrid = 80 * HEADS;                      // 640 blocks of 256 threads
  int scoreGrid = (N_NODES + 15) / 16;            // 625 score blocks
  int aggGrid = ((N_NODES + 31) / 32) * 8;        // 2504 blocks: 32 dst x 1 head

  // ---- ONE prep dispatch: A/W1/W2 splits + bucket CSR + wt1/wt2 ----
  {
    int totalA = RBPAD * 64 * 16;             // K8=64
    int nbA = (totalA + 255) / 256;           // 2560
    int totalB = 64 * 64 * 16;                // W1: 1024 rows, K8=64
    int nbB = (totalB + 255) / 256;           // 256
    int totalB2 = 64 * 16 * 16;               // W2: 1024 rows, K8=16
    int nbB2 = (totalB2 + 255) / 256;         // 64
    int nbE = (N_EDGES + 255) / 256;          // 625
    int nbW = 40;                             // 32 wt1 + 8 wt2
    split_frag2<<<nbA + nbB + nbB2 + nbE + nbW, 256, 0, stream>>>(
        x, Afh, N_NODES, 64, totalA, nbA,
        W1, Bfh, HEADS * HID, 64, totalB, nbB,
        W2, Bfh2, totalB2, nbB2,
        esrc, edst, deg, slots, ovf, cnt, N_EDGES,
        a1, a2, wt1, wt2);
  }

  // ---- Layer 1: GEMM + fused score GEMV in one dispatch ----
  gemm_score<<<gemmGrid + scoreGrid, 256, 0, stream>>>(
      Afh, Bfh, hb, N_NODES, N_FEAT, gemmGrid, x, wt1, si, sj, N_NODES);
  gat_aggregate9<<<aggGrid, 512, 0, stream>>>(hb, si, sj, deg, slots, ovf, cnt,
                                              aggb, N_NODES);
  headmean_frag2<<<(N_NODES + 15) / 16, 256, 0, stream>>>(aggb, Afh, N_NODES,
                                                          wt2, si, sj);

  // ---- Layer 2 ----
  gemm_score<<<gemmGrid, 256, 0, stream>>>(
      Afh, Bfh2, hb, N_NODES, HID, gemmGrid, nullptr, nullptr, nullptr, nullptr, 0);
  gat_aggregate9<<<aggGrid, 512, 0, stream>>>(hb, si, sj, deg, slots, ovf, cnt,
                                              aggb, N_NODES);

  // ---- head-mean + pooling, then MLP head ----
  headmean_pool<<<(N_NODES + 15) / 16, 256, 0, stream>>>(aggb, g, N_NODES);
  mlp_kernel<<<1, 128, 0, stream>>>(g, ln_g, ln_b, Wl1, bl1, Wl2, bl2, Wl3, bl3,
                                    out, 1.0f / N_NODES);
}